// Round 13
// baseline (290.846 us; speedup 1.0000x reference)
//
#include <hip/hip_runtime.h>
#include <math.h>

#define NC    30
#define D     300
#define WIN   100
#define TOPK  25
#define NEGV  -1e10f
#define NKS   19           // 19*16 = 304 >= 300

typedef __attribute__((ext_vector_type(8)))  short short8;
typedef __attribute__((ext_vector_type(16))) float f32x16;
typedef __attribute__((ext_vector_type(4)))  unsigned int uint4v;

__device__ inline unsigned short bftrunc(float f) {
    return (unsigned short)(__builtin_bit_cast(unsigned int, f) >> 16);
}
__device__ inline float bfval(unsigned short b) {
    return __builtin_bit_cast(float, (unsigned int)b << 16);
}
__device__ inline void split8(const float* v, short8& hi, short8& lo) {
    #pragma unroll
    for (int j = 0; j < 8; ++j) {
        unsigned short hb = bftrunc(v[j]);
        float lf = v[j] - bfval(hb);
        hi[j] = (short)hb;
        lo[j] = (short)bftrunc(lf);
    }
}

__global__ __launch_bounds__(256, 4)
void fused_mention_kernel(const float* __restrict__ E,
                          const float* __restrict__ T,
                          const void*  __restrict__ maskp,
                          const float* __restrict__ B1,
                          const float* __restrict__ B2,
                          float* __restrict__ out)
{
    const int n     = blockIdx.x;
    const int tid   = threadIdx.x;
    const int wv    = tid >> 6;
    const int lane  = tid & 63;
    const int arow  = lane & 31;          // candidate row (A) / token col (B)
    const int khalf = (lane >> 5) * 8;

    __shared__ float ts[WIN];
    __shared__ __align__(16) float fcsL[D];   // fallback path only
    __shared__ int   bidxL[TOPK];             // fallback path only
    __shared__ float bprobL[TOPK];            // fallback path only
    __shared__ float vredS[4][32];

    // ---- mask dtype detect, per-wave: int32 has zero bytes at %4!=0 ----
    int found;
    {
        const uint4v* m4 = (const uint4v*)maskp;
        uint4v w = m4[wv * 64 + lane];
        found = (((w.x | w.y | w.z | w.w) & 0xFFFFFF00u) != 0u) ? 1 : 0;
    }
    const bool bytemask = (__ballot(found) != 0ULL);

    // ---- valid-prefix length L, per-wave ----
    int v0m = 0, v1m = 0;
    if (bytemask) {
        const unsigned char* mb = (const unsigned char*)maskp + (size_t)n * WIN;
        v0m = mb[lane] != 0;
        if (lane + 64 < WIN) v1m = mb[lane + 64] != 0;
    } else {
        const int* mi = (const int*)maskp + (size_t)n * WIN;
        v0m = mi[lane] != 0;
        if (lane + 64 < WIN) v1m = mi[lane + 64] != 0;
    }
    const int L  = __popcll(__ballot(v0m)) + __popcll(__ballot(v1m));
    const int Lc = (L > 0) ? L : 1;

    // ---- B1 == B2 check (enables vals-from-scores identity) ----
    int neq = 0;
    #pragma unroll
    for (int k = 0; k < 5; ++k) {
        const int d = lane + 64 * k;
        if (d < D) neq |= (B1[d] != B2[d]) ? 1 : 0;
    }
    const bool beq = (__ballot(neq) == 0ULL);   // block-uniform

    const int ntiles = (L + 31) >> 5;
    const int t0 = wv * 32;
    const float* Tn = T + (size_t)n * WIN * D;
    const float* bp = Tn + (size_t)min(t0 + arow, Lc - 1) * D;
    const float* ep = E + ((size_t)n * NC + min(arow, NC - 1)) * D;

    // ---- score GEMM: wave wv owns tile wv; A prepped inline from global ----
    f32x16 c;
    #pragma unroll
    for (int r = 0; r < 16; ++r) c[r] = 0.f;
    float m = NEGV;

    if (wv < ntiles) {
        f32x16 cB;
        #pragma unroll
        for (int r = 0; r < 16; ++r) cB[r] = 0.f;

        float4 q0r[4], q1r[4];
        #pragma unroll
        for (int s = 0; s < 4; ++s) {             // preload T steps 0..3
            const int kb = 16 * s + khalf;
            q0r[s] = *reinterpret_cast<const float4*>(bp + kb);
            q1r[s] = *reinterpret_cast<const float4*>(bp + kb + 4);
        }
        #pragma unroll
        for (int s = 0; s < NKS; ++s) {
            const int slot = s & 3;               // static after unroll
            float4 q0 = q0r[slot], q1 = q1r[slot];
            if (s + 4 < NKS) {                    // prefetch T step s+4
                const int kb2 = 16 * (s + 4) + khalf;
                q0r[slot] = *reinterpret_cast<const float4*>(bp + kb2);
                q1r[slot] = (kb2 + 8 <= D)
                          ? *reinterpret_cast<const float4*>(bp + kb2 + 4)
                          : make_float4(0.f, 0.f, 0.f, 0.f);
            }
            const int kb = 16 * s + khalf;
            // A inline: E row (L1-shared across waves) x B2
            float av[8] = {0.f, 0.f, 0.f, 0.f, 0.f, 0.f, 0.f, 0.f};
            {
                float4 e0 = *reinterpret_cast<const float4*>(ep + kb);
                float4 g0 = *reinterpret_cast<const float4*>(B2 + kb);
                av[0] = e0.x * g0.x; av[1] = e0.y * g0.y;
                av[2] = e0.z * g0.z; av[3] = e0.w * g0.w;
                if (kb + 8 <= D) {
                    float4 e1 = *reinterpret_cast<const float4*>(ep + kb + 4);
                    float4 g1 = *reinterpret_cast<const float4*>(B2 + kb + 4);
                    av[4] = e1.x * g1.x; av[5] = e1.y * g1.y;
                    av[6] = e1.z * g1.z; av[7] = e1.w * g1.w;
                }
            }
            short8 ah, al;
            split8(av, ah, al);
            float v[8] = {q0.x, q0.y, q0.z, q0.w, q1.x, q1.y, q1.z, q1.w};
            short8 bh, bl;
            split8(v, bh, bl);
            if (s & 1) {      // dual accumulators: halve the MFMA dep chain
                cB = __builtin_amdgcn_mfma_f32_32x32x16_bf16(ah, bh, cB, 0, 0, 0);
                cB = __builtin_amdgcn_mfma_f32_32x32x16_bf16(al, bh, cB, 0, 0, 0);
                cB = __builtin_amdgcn_mfma_f32_32x32x16_bf16(ah, bl, cB, 0, 0, 0);
            } else {
                c  = __builtin_amdgcn_mfma_f32_32x32x16_bf16(ah, bh, c, 0, 0, 0);
                c  = __builtin_amdgcn_mfma_f32_32x32x16_bf16(al, bh, c, 0, 0, 0);
                c  = __builtin_amdgcn_mfma_f32_32x32x16_bf16(ah, bl, c, 0, 0, 0);
            }
        }
        #pragma unroll
        for (int r = 0; r < 16; ++r) c[r] += cB[r];
        // pad candidate rows 30,31 (regs 14,15 on lanes >= 32) -> -inf
        if (lane >= 32) { c[14] = -__builtin_inff(); c[15] = -__builtin_inff(); }
        m = c[0];
        #pragma unroll
        for (int r = 1; r < 16; ++r) m = fmaxf(m, c[r]);
        m = fmaxf(m, __shfl_xor(m, 32));
    }
    // every wave fully owns its ts range (incl. NEGV tail / idle tiles)
    if (lane < 32 && t0 + arow < WIN)
        ts[t0 + arow] = (wv < ntiles && t0 + arow < L) ? m : NEGV;
    __syncthreads();                              // ts complete

    // ---- redundant per-wave top-25 (lower-index tie-break) + softmax ----
    const float NINF = -__builtin_inff();
    float va = ts[lane];
    float vb = (lane + 64 < WIN) ? ts[lane + 64] : NINF;
    float sc = 0.f, mx = 0.f;
    int   ixr = 0;
    for (int t = 0; t < TOPK; ++t) {
        float v0; int i0;
        if (vb > va) { v0 = vb; i0 = lane + 64; } else { v0 = va; i0 = lane; }
        #pragma unroll
        for (int s = 32; s >= 1; s >>= 1) {
            float ov = __shfl_xor(v0, s);
            int   oi = __shfl_xor(i0, s);
            if (ov > v0 || (ov == v0 && oi < i0)) { v0 = ov; i0 = oi; }
        }
        if (t == 0) mx = v0;
        if (lane == t) { sc = v0; ixr = i0; }
        if (i0 == lane) va = NINF;
        else if (i0 == lane + 64) vb = NINF;
    }
    float p = (lane < TOPK) ? expf(sc - mx) : 0.f;
    float s1 = p;
    #pragma unroll
    for (int s = 32; s >= 1; s >>= 1) s1 += __shfl_xor(s1, s);
    p = p / s1;
    float s2 = p;   // reference renormalizes a second time
    #pragma unroll
    for (int s = 32; s >= 1; s >>= 1) s2 += __shfl_xor(s2, s);
    p = p / s2;

    if (beq) {
        // ---- vals[c] = sum_t p_t * S[c, idx_t] straight from accumulators ----
        float vacc[16];
        #pragma unroll
        for (int r = 0; r < 16; ++r) vacc[r] = 0.f;
        if (wv < ntiles) {
            for (int t = 0; t < TOPK; ++t) {
                const float pb = __shfl(p, t);
                const int   ib = __shfl(ixr, t);
                if ((ib >> 5) == wv) {            // wave-uniform
                    if ((lane & 31) == (ib & 31)) {
                        #pragma unroll
                        for (int r = 0; r < 16; ++r) vacc[r] += pb * c[r];
                    }
                }
            }
        }
        #pragma unroll
        for (int r = 0; r < 16; ++r) {
            float s = vacc[r];
            s += __shfl_xor(s, 1);  s += __shfl_xor(s, 2);
            s += __shfl_xor(s, 4);  s += __shfl_xor(s, 8);
            s += __shfl_xor(s, 16);
            vacc[r] = s;
        }
        if ((lane & 31) == 0) {                   // lanes 0 and 32
            #pragma unroll
            for (int r = 0; r < 16; ++r) {
                const int row = (r & 3) + 8 * (r >> 2) + 4 * (lane >> 5);
                vredS[wv][row] = vacc[r];
            }
        }
        __syncthreads();
        if (tid < NC)
            out[(size_t)n * NC + tid] = vredS[0][tid] + vredS[1][tid]
                                      + vredS[2][tid] + vredS[3][tid];
    } else {
        // ---- fallback (B1 != B2): fcs gather + vals with E re-read ----
        if (wv == 0 && lane < TOPK) { bprobL[lane] = p; bidxL[lane] = ixr; }
        __syncthreads();
        for (int d = tid; d < D; d += 256) {
            float acc = 0.f;
            #pragma unroll 5
            for (int t = 0; t < TOPK; ++t)
                acc += bprobL[t] * Tn[(size_t)bidxL[t] * D + d];
            fcsL[d] = acc;
        }
        __syncthreads();
        {
            const int dg = tid >> 5;
            const int d0 = dg * 40;
            const bool full = (dg < 7);
            const int cg = arow;
            const bool cok = (cg < NC);
            float acc2 = 0.f;
            const float* Erow = E + ((size_t)n * NC + (cok ? cg : 0)) * D + d0;
            #pragma unroll
            for (int j = 0; j < 5; ++j) {
                float4 ev = *reinterpret_cast<const float4*>(Erow + 4 * j);
                float4 bv = *reinterpret_cast<const float4*>(B1 + d0 + 4 * j);
                float4 fv = *reinterpret_cast<const float4*>(fcsL + d0 + 4 * j);
                acc2 += ev.x * bv.x * fv.x + ev.y * bv.y * fv.y
                      + ev.z * bv.z * fv.z + ev.w * bv.w * fv.w;
            }
            if (full) {
                #pragma unroll
                for (int j = 5; j < 10; ++j) {
                    float4 ev = *reinterpret_cast<const float4*>(Erow + 4 * j);
                    float4 bv = *reinterpret_cast<const float4*>(B1 + d0 + 4 * j);
                    float4 fv = *reinterpret_cast<const float4*>(fcsL + d0 + 4 * j);
                    acc2 += ev.x * bv.x * fv.x + ev.y * bv.y * fv.y
                          + ev.z * bv.z * fv.z + ev.w * bv.w * fv.w;
                }
            }
            if (!cok) acc2 = 0.f;
            acc2 += __shfl_xor(acc2, 32);
            if (lane < 32) vredS[wv][cg] = acc2;
        }
        __syncthreads();
        if (tid < NC)
            out[(size_t)n * NC + tid] = vredS[0][tid] + vredS[1][tid]
                                      + vredS[2][tid] + vredS[3][tid];
    }
}

extern "C" void kernel_launch(void* const* d_in, const int* in_sizes, int n_in,
                              void* d_out, int out_size, void* d_ws, size_t ws_size,
                              hipStream_t stream)
{
    const float* E  = (const float*)d_in[0];
    const float* T  = (const float*)d_in[1];
    const void*  M  = d_in[2];
    const float* B1 = (const float*)d_in[3];
    const float* B2 = (const float*)d_in[4];
    float* out = (float*)d_out;
    const int n = in_sizes[0] / (NC * D);   // number of mentions
    fused_mention_kernel<<<n, 256, 0, stream>>>(E, T, M, B1, B2, out);
}